// Round 11
// baseline (274.022 us; speedup 1.0000x reference)
//
#include <hip/hip_runtime.h>
#include <hip/hip_cooperative_groups.h>

namespace cg = cooperative_groups;

// Problem constants (fixed by the reference).
#define NNODES 100000
#define NEDGES 800000
#define DIN    128
#define HID    64
#define EMB    32
#define NIDX   50000
#define BN_EPS 1e-5f

#define NCHK 64                   // partition chunks (64 -> ~8-edge runs per bucket, 64B)
#define EC   (NEDGES / NCHK)      // 12500 edges per chunk
#define NB   ((NNODES + 63) / 64) // 1563 row-buckets of 64 rows
#define PF   16                   // bucket fractions per chunk (scatter parallelism)
#define NBF  ((NB + PF - 1) / PF) // 98 buckets per fraction
#define GBM  ((NNODES + 63) / 64) // 1563 row-tile blocks
#define SMSZ 17920                // shared scratch (fits all kernel phases)

typedef __attribute__((ext_vector_type(8))) short short8;   // 8 bf16 = 4 VGPR
typedef __attribute__((ext_vector_type(4))) float f32x4;    // MFMA C/D

__device__ inline unsigned short f2bf(float f) {            // RNE, matches HW
    unsigned u = __float_as_uint(f);
    unsigned r = u + 0x7FFFu + ((u >> 16) & 1u);
    return (unsigned short)(r >> 16);
}
__device__ inline float bf2f_lo(unsigned u) { return __uint_as_float(u << 16); }
__device__ inline float bf2f_hi(unsigned u) { return __uint_as_float(u & 0xffff0000u); }

// ---------------------------------------------------------------------------
// W pre-pack: fp32 [Wn|Wg] -> bf16 B-fragment-major (GEMM B-loads coalesced).
// ---------------------------------------------------------------------------

__device__ inline void pack_seg(const float* __restrict__ Wn, const float* __restrict__ Wg,
                                unsigned short* __restrict__ Wp, int HOUT, int l2nt, int f) {
    int j = f & 7, lane = (f >> 3) & 63, g = f >> 9;
    int tt = g & ((1 << l2nt) - 1), kb = g >> l2nt;
    int k = kb * 32 + ((lane >> 4) * 8) + j;
    int nn = tt * 16 + (lane & 15);
    float v = (nn < HOUT) ? Wn[k * HOUT + nn] : Wg[k * HOUT + (nn - HOUT)];
    Wp[f] = f2bf(v);
}

// ---------------------------------------------------------------------------
// K1: blocks [0,NCHK): per-chunk bucket histogram -> Bcnt4[chunk][b]
//     + bucket totals bTot[b] via global atomics (breaks prefix/scan dep).
//     blocks [NCHK,NCHK+MB): mark[idx[j]] = 1
//     blocks [NCHK+MB,..): W pre-pack (all 3 layers)  -- all independent.
// ---------------------------------------------------------------------------

__global__ __launch_bounds__(256) void histpack_k(
    const int* __restrict__ rows, int* __restrict__ Bcnt4, int* __restrict__ bTot,
    const int* __restrict__ idx, int* __restrict__ mark,
    const float* Wn0, const float* Wg0, const float* Wn1,
    const float* Wg1, const float* WnL, const float* WgL,
    unsigned short* Wp0, unsigned short* Wp1, unsigned short* WpL, int MB)
{
    int blk = blockIdx.x;
    int t = threadIdx.x;
    if (blk >= NCHK + MB) {
        int f = (blk - NCHK - MB) * 256 + t;
        if (f < 16384)      pack_seg(Wn0, Wg0, Wp0, 64, 3, f);           // 128x128
        else if (f < 24576) pack_seg(Wn1, Wg1, Wp1, 64, 3, f - 16384);   // 64x128
        else if (f < 28672) pack_seg(WnL, WgL, WpL, 32, 2, f - 24576);   // 64x64
        return;
    }
    if (blk >= NCHK) {
        int j = (blk - NCHK) * 256 + t;
        if (j < NIDX) mark[idx[j]] = 1;
        return;
    }
    __shared__ int hist[NB];
    for (int b = t; b < NB; b += 256) hist[b] = 0;
    __syncthreads();
    const int* rbase = rows + blk * EC;
    for (int i4 = t; i4 < EC / 4; i4 += 256) {           // 3125 int4 reads
        int4 r4 = *(const int4*)&rbase[i4 * 4];
        atomicAdd(&hist[r4.x >> 6], 1);
        atomicAdd(&hist[r4.y >> 6], 1);
        atomicAdd(&hist[r4.z >> 6], 1);
        atomicAdd(&hist[r4.w >> 6], 1);
    }
    __syncthreads();
    for (int b = t; b < NB; b += 256) {
        int h = hist[b];
        Bcnt4[blk * NB + b] = h;
        if (h) atomicAdd(&bTot[b], h);                   // device-scope
    }
}

// scan_k: ONE dispatch, two independent jobs (both depend only on histpack):
//   blocks 0..6: per-bucket prefix over chunks -> BcntT[chunk][b]
//   block 7:     exclusive scan of bTot -> bBase (bucket bases)
__global__ __launch_bounds__(256) void scan_k(
    const int* __restrict__ Bcnt4, int* __restrict__ BcntT,
    const int* __restrict__ bTot, int* __restrict__ bBase)
{
    int t = threadIdx.x;
    if (blockIdx.x < 7) {
        int b = blockIdx.x * 256 + t;
        if (b >= NB) return;
        int run = 0;
        for (int c = 0; c < NCHK; c++) {
            BcntT[c * NB + b] = run;     // coalesced read & write
            run += Bcnt4[c * NB + b];
        }
        return;
    }
    __shared__ int s[256];
    int v[7], loc = 0;
#pragma unroll
    for (int i = 0; i < 7; i++) {
        int ix = t * 7 + i;
        v[i] = loc;
        loc += (ix < NB) ? bTot[ix] : 0;
    }
    s[t] = loc;
    __syncthreads();
    for (int off = 1; off < 256; off <<= 1) {
        int a = (t >= off) ? s[t - off] : 0;
        __syncthreads();
        s[t] += a;
        __syncthreads();
    }
    int base = s[t] - loc;
#pragma unroll
    for (int i = 0; i < 7; i++) {
        int ix = t * 7 + i;
        if (ix < NB) bBase[ix] = base + v[i];
    }
    if (t == 255) bBase[NB] = NEDGES;
}

// ---------------------------------------------------------------------------
// bfinal+spmm0 FUSED v2: one block per bucket (64 rows, ~512 edges).
// Single ebuf pass; registers -> LDS-sorted es2 -> coalesced cs dump; spmm0
// consumes edges from LDS. Overflow (>1024 edges/bucket) via global cs.
// ---------------------------------------------------------------------------

__global__ __launch_bounds__(256) void bfinal_spmm0_k(
    const uint2* __restrict__ ebuf, const int* __restrict__ bBase,
    int* __restrict__ rowptr, int2* __restrict__ cs,
    const unsigned short* __restrict__ Hgb, unsigned short* __restrict__ S,
    float* __restrict__ stats, int n)
{
    constexpr int ECAP = 1024;
    __shared__ int hist[64], sc[64], cur[64];
    __shared__ int2 es2[ECAP];               // bucket-local sorted edges
    __shared__ float rs[16][HID], rq[16][HID];
    int b = blockIdx.x, t = threadIdx.x;
    int e0 = bBase[b], e1 = bBase[b + 1];
    int cnt = e1 - e0;
    int r0 = b << 6;
    if (t < 64) hist[t] = 0;
    __syncthreads();

    // pass 1: load edges once (named registers), build histogram
    uint2 ev0, ev1, ev2, ev3;
    bool h0 = t < cnt, h1 = t + 256 < cnt, h2 = t + 512 < cnt, h3 = t + 768 < cnt;
    if (h0) { ev0 = ebuf[e0 + t];       atomicAdd(&hist[(ev0.x >> 20) & 63], 1); }
    if (h1) { ev1 = ebuf[e0 + t + 256]; atomicAdd(&hist[(ev1.x >> 20) & 63], 1); }
    if (h2) { ev2 = ebuf[e0 + t + 512]; atomicAdd(&hist[(ev2.x >> 20) & 63], 1); }
    if (h3) { ev3 = ebuf[e0 + t + 768]; atomicAdd(&hist[(ev3.x >> 20) & 63], 1); }
    for (int i = t + ECAP; i < cnt; i += 256) {          // overflow tail (rare)
        uint2 v = ebuf[e0 + i];
        atomicAdd(&hist[(v.x >> 20) & 63], 1);
    }
    __syncthreads();
    if (t == 0) {
        int run = 0;                                     // LOCAL (0-based) scan
        for (int j = 0; j < 64; j++) { sc[j] = run; run += hist[j]; }
    }
    __syncthreads();
    if (t < 64) {
        cur[t] = sc[t];
        int r = r0 + t;
        if (r < NNODES) rowptr[r] = e0 + sc[t];
    }
    if (b == NB - 1 && t == 0) rowptr[NNODES] = NEDGES;
    __syncthreads();

    // pass 2: scatter registers -> es2 (LDS), overflow -> cs directly
#define SCAT(V)                                                          \
    {                                                                    \
        int p = atomicAdd(&cur[((V).x >> 20) & 63], 1);                  \
        int2 pay = make_int2((int)((V).x & 0xFFFFF), (int)(V).y);        \
        if (p < ECAP) es2[p] = pay; else cs[e0 + p] = pay;               \
    }
    if (h0) SCAT(ev0)
    if (h1) SCAT(ev1)
    if (h2) SCAT(ev2)
    if (h3) SCAT(ev3)
    for (int i = t + ECAP; i < cnt; i += 256) {
        uint2 v = ebuf[e0 + i];
        SCAT(v)
    }
#undef SCAT
    __syncthreads();                 // es2 complete; overflow cs writes drained

    // pass 3: coalesced dump es2 -> cs
    int scnt = min(cnt, ECAP);
    for (int i = t; i < scnt; i += 256) cs[e0 + i] = es2[i];

    // ---- spmm0 phase: 16 groups x 16 lanes, 4 consecutive rows per group ----
    const int lane = t & 15, g = t >> 4;
    const int c0 = lane * 4;
    float4 sum = make_float4(0.f, 0.f, 0.f, 0.f);
    float4 sq  = make_float4(0.f, 0.f, 0.f, 0.f);
#define FE(i) ((i) < ECAP ? es2[(i)] : cs[e0 + (i)])
#pragma unroll
    for (int rr = 0; rr < 4; rr++) {
        int lr = g * 4 + rr;
        int row = r0 + lr;
        if (row >= n) break;
        int le0 = sc[lr], le1 = sc[lr] + hist[lr];       // local indices
        uint2 h = *(const uint2*)&S[(size_t)row * HID + c0];
        float4 a0 = make_float4(bf2f_lo(h.x), bf2f_hi(h.x), bf2f_lo(h.y), bf2f_hi(h.y));
        float4 a1 = make_float4(0.f, 0.f, 0.f, 0.f), a2 = a1, a3 = a1;
        int e = le0;
        for (; e + 3 < le1; e += 4) {
            int2 p0 = FE(e), p1 = FE(e + 1), p2 = FE(e + 2), p3 = FE(e + 3);
            float v0 = __int_as_float(p0.y), v1 = __int_as_float(p1.y);
            float v2 = __int_as_float(p2.y), v3 = __int_as_float(p3.y);
            uint2 h0v = *(const uint2*)&Hgb[(size_t)p0.x * HID + c0];
            uint2 h1v = *(const uint2*)&Hgb[(size_t)p1.x * HID + c0];
            uint2 h2v = *(const uint2*)&Hgb[(size_t)p2.x * HID + c0];
            uint2 h3v = *(const uint2*)&Hgb[(size_t)p3.x * HID + c0];
            a0.x += v0 * bf2f_lo(h0v.x); a0.y += v0 * bf2f_hi(h0v.x);
            a0.z += v0 * bf2f_lo(h0v.y); a0.w += v0 * bf2f_hi(h0v.y);
            a1.x += v1 * bf2f_lo(h1v.x); a1.y += v1 * bf2f_hi(h1v.x);
            a1.z += v1 * bf2f_lo(h1v.y); a1.w += v1 * bf2f_hi(h1v.y);
            a2.x += v2 * bf2f_lo(h2v.x); a2.y += v2 * bf2f_hi(h2v.x);
            a2.z += v2 * bf2f_lo(h2v.y); a2.w += v2 * bf2f_hi(h2v.y);
            a3.x += v3 * bf2f_lo(h3v.x); a3.y += v3 * bf2f_hi(h3v.x);
            a3.z += v3 * bf2f_lo(h3v.y); a3.w += v3 * bf2f_hi(h3v.y);
        }
        for (; e < le1; e++) {
            int2 p = FE(e);
            float v = __int_as_float(p.y);
            uint2 hh = *(const uint2*)&Hgb[(size_t)p.x * HID + c0];
            a0.x += v * bf2f_lo(hh.x); a0.y += v * bf2f_hi(hh.x);
            a0.z += v * bf2f_lo(hh.y); a0.w += v * bf2f_hi(hh.y);
        }
        float4 acc = make_float4(a0.x + a1.x + a2.x + a3.x, a0.y + a1.y + a2.y + a3.y,
                                 a0.z + a1.z + a2.z + a3.z, a0.w + a1.w + a2.w + a3.w);
        uint2 o;
        o.x = (unsigned)f2bf(acc.x) | ((unsigned)f2bf(acc.y) << 16);
        o.y = (unsigned)f2bf(acc.z) | ((unsigned)f2bf(acc.w) << 16);
        *(uint2*)&S[(size_t)row * HID + c0] = o;
        sum.x += acc.x; sum.y += acc.y; sum.z += acc.z; sum.w += acc.w;
        sq.x += acc.x * acc.x; sq.y += acc.y * acc.y;
        sq.z += acc.z * acc.z; sq.w += acc.w * acc.w;
    }
#undef FE

    *(float4*)&rs[g][c0] = sum;
    *(float4*)&rq[g][c0] = sq;
    __syncthreads();
    if (t < HID) {
        float a = 0.f, bb = 0.f;
        for (int w = 0; w < 16; w++) { a += rs[w][t]; bb += rq[w][t]; }
        int stripe = b & 7;
        atomicAdd(&stats[stripe * 128 + t], a);
        atomicAdd(&stats[stripe * 128 + HID + t], bb);
    }
}

// ---------------------------------------------------------------------------
// MFMA dual-GEMM body (shared scratch passed in -> usable from fused kernels).
// ---------------------------------------------------------------------------

template <int K, int HOUT, bool AFF, bool XBF, bool HNBF>
__device__ void gemm_body(const void* __restrict__ Xv, const unsigned short* __restrict__ Wp,
                          const float* __restrict__ bnA, const float* __restrict__ bnB,
                          const float* __restrict__ bgA,
                          const float* __restrict__ sums, const float* __restrict__ gamma,
                          const float* __restrict__ beta,
                          float* __restrict__ Hnf, unsigned short* __restrict__ Hnb,
                          unsigned short* __restrict__ Hgb, int n, int blk, char* sm)
{
    constexpr int NT = 2 * HOUT / 16, NKB = K / 32;
    constexpr int RS = K + 8;                       // staging row stride (shorts)
    constexpr int OC = HNBF ? 2 * HOUT : HOUT;      // cols staged through LDS in epilogue
    constexpr int RSE = OC + 8;                     // epilogue row stride (shorts, 16B mult)
    constexpr int XSZ = (RS > RSE) ? RS : RSE;
    static_assert(64 * XSZ * 2 + 512 <= SMSZ, "smem budget");
    unsigned short* Xs = (unsigned short*)sm;
    float* sSc = (float*)(sm + 64 * XSZ * 2);
    float* sSh = sSc + 64;

    const int row0 = blk * 64;
    const int t = threadIdx.x;

    if (AFF) {               // in-block BN finalize: 1KB of reads, once per block
        if (t < 64) {
            float sum = 0.f, sq = 0.f;
#pragma unroll
            for (int s = 0; s < 8; s++) { sum += sums[s * 128 + t]; sq += sums[s * 128 + 64 + t]; }
            float m = sum / (float)NNODES;
            float var = sq / (float)NNODES - m * m;
            float sc = gamma[t] * rsqrtf(var + BN_EPS);
            sSc[t] = sc; sSh[t] = beta[t] - m * sc;
        }
        __syncthreads();
    }

    constexpr int SIT = K / 32;      // staging iterations per thread (256 thr)
    if constexpr (XBF) {
        uint4 u[SIT];
#pragma unroll
        for (int it = 0; it < SIT; it++) {
            int li = it * 256 + t;
            int rr = row0 + li / (K / 8);
            int k8 = (li % (K / 8)) * 8;
            int rc = rr < n ? rr : n - 1;
            u[it] = *(const uint4*)((const unsigned short*)Xv + (size_t)rc * K + k8);
        }
#pragma unroll
        for (int it = 0; it < SIT; it++) {
            int li = it * 256 + t;
            int r  = li / (K / 8);
            int k8 = (li % (K / 8)) * 8;
            float v[8];
            v[0] = bf2f_lo(u[it].x); v[1] = bf2f_hi(u[it].x);
            v[2] = bf2f_lo(u[it].y); v[3] = bf2f_hi(u[it].y);
            v[4] = bf2f_lo(u[it].z); v[5] = bf2f_hi(u[it].z);
            v[6] = bf2f_lo(u[it].w); v[7] = bf2f_hi(u[it].w);
            if (AFF) {
#pragma unroll
                for (int i = 0; i < 8; i++) v[i] = fmaxf(v[i] * sSc[k8 + i] + sSh[k8 + i], 0.f);
            }
            uint4 o;
            o.x = (unsigned)f2bf(v[0]) | ((unsigned)f2bf(v[1]) << 16);
            o.y = (unsigned)f2bf(v[2]) | ((unsigned)f2bf(v[3]) << 16);
            o.z = (unsigned)f2bf(v[4]) | ((unsigned)f2bf(v[5]) << 16);
            o.w = (unsigned)f2bf(v[6]) | ((unsigned)f2bf(v[7]) << 16);
            *(uint4*)&Xs[r * RS + k8] = o;
        }
    } else {
        const float* Xf = (const float*)Xv;
        float4 a[SIT], b[SIT];
#pragma unroll
        for (int it = 0; it < SIT; it++) {
            int li = it * 256 + t;
            int rr = row0 + li / (K / 8);
            int k8 = (li % (K / 8)) * 8;
            int rc = rr < n ? rr : n - 1;
            a[it] = *(const float4*)&Xf[(size_t)rc * K + k8];
            b[it] = *(const float4*)&Xf[(size_t)rc * K + k8 + 4];
        }
#pragma unroll
        for (int it = 0; it < SIT; it++) {
            int li = it * 256 + t;
            int r  = li / (K / 8);
            int k8 = (li % (K / 8)) * 8;
            float v[8] = { a[it].x, a[it].y, a[it].z, a[it].w,
                           b[it].x, b[it].y, b[it].z, b[it].w };
            if (AFF) {
#pragma unroll
                for (int i = 0; i < 8; i++) v[i] = fmaxf(v[i] * sSc[k8 + i] + sSh[k8 + i], 0.f);
            }
            uint4 o;
            o.x = (unsigned)f2bf(v[0]) | ((unsigned)f2bf(v[1]) << 16);
            o.y = (unsigned)f2bf(v[2]) | ((unsigned)f2bf(v[3]) << 16);
            o.z = (unsigned)f2bf(v[4]) | ((unsigned)f2bf(v[5]) << 16);
            o.w = (unsigned)f2bf(v[6]) | ((unsigned)f2bf(v[7]) << 16);
            *(uint4*)&Xs[r * RS + k8] = o;
        }
    }
    __syncthreads();

    const int wave = t >> 6, lane = t & 63;
    const int q = lane >> 4, mrow = lane & 15;

    f32x4 acc[NT];
#pragma unroll
    for (int i = 0; i < NT; i++) acc[i] = (f32x4){0.f, 0.f, 0.f, 0.f};

    const short8* wp8 = (const short8*)Wp;
#pragma unroll
    for (int kb = 0; kb < NKB; kb++) {
        short8 va = *(const short8*)&Xs[(wave * 16 + mrow) * RS + kb * 32 + q * 8];
#pragma unroll
        for (int tt = 0; tt < NT; tt++) {
            short8 vb = wp8[(kb * NT + tt) * 64 + lane];   // coalesced dwordx4
            acc[tt] = __builtin_amdgcn_mfma_f32_16x16x32_bf16(va, vb, acc[tt], 0, 0, 0);
        }
    }

    // Epilogue. C/D: col = lane&15 (tile tt), row = q*4 + reg.
    __syncthreads();          // all waves done reading staging Xs
#pragma unroll
    for (int tt = 0; tt < NT; tt++) {
        int nglob = tt * 16 + mrow;
        bool nside = (nglob < HOUT);
        int c = nside ? nglob : (nglob - HOUT);
        float bias = 0.f;
        if (nside) {
            if (bnA) bias += bnA[c];
            if (bnB) bias += bnB[c];
        } else if (bgA) {
            bias += bgA[c];
        }
        if (HNBF || !nside) {
            int cc = HNBF ? nglob : c;
#pragma unroll
            for (int r = 0; r < 4; r++)
                Xs[(wave * 16 + q * 4 + r) * RSE + cc] = f2bf(acc[tt][r] + bias);
        } else {
#pragma unroll
            for (int r = 0; r < 4; r++) {
                int rr = row0 + wave * 16 + q * 4 + r;
                if (rr < n) Hnf[(size_t)rr * HOUT + c] = acc[tt][r] + bias;
            }
        }
    }
    __syncthreads();
    constexpr int J = OC / 8;                 // uint4 per row
#pragma unroll
    for (int u2 = 0; u2 < (64 * J) / 256; u2++) {
        int li = u2 * 256 + t;
        int r = li / J, j = li % J;
        int rr = row0 + r;
        if (rr < n) {
            uint4 v = *(const uint4*)&Xs[r * RSE + j * 8];
            int c8 = j * 8;
            if (HNBF && c8 < HOUT)
                *(uint4*)&Hnb[(size_t)rr * HOUT + c8] = v;
            else
                *(uint4*)&Hgb[(size_t)rr * HOUT + (HNBF ? c8 - HOUT : c8)] = v;
        }
    }
}

// K_C: partition (XCD-colocated siblings, prefetched stream) + layer-0 GEMM.
__global__ __launch_bounds__(256) void part_gemm0_k(
    const int* __restrict__ rows, const int* __restrict__ cols,
    const float* __restrict__ vals, const int* __restrict__ BcntT,
    const int* __restrict__ bBase, uint2* __restrict__ ebuf,
    const float* __restrict__ X, const unsigned short* __restrict__ Wp0,
    const float* __restrict__ bn0, const float* __restrict__ ab0, const float* __restrict__ bg0,
    unsigned short* __restrict__ Hn0b, unsigned short* __restrict__ Hgb, int n)
{
    __shared__ alignas(16) char sm[SMSZ];
    if ((int)blockIdx.x < NCHK * PF) {
        int* cur = (int*)sm;
        int t = threadIdx.x;
        int blk = blockIdx.x % NCHK;          // sibling co-location: i%8 == blk%8
        int pf  = blockIdx.x / NCHK;
        int b0 = pf * NBF, b1 = (pf == PF - 1) ? NB : (b0 + NBF);
        for (int b = b0 + t; b < b1; b += 256)
            cur[b - b0] = bBase[b] + BcntT[blk * NB + b];
        __syncthreads();
        constexpr int EC4 = EC / 4;           // 3125 int4 reads per chunk stream
        const int*   rbase = rows + blk * EC;
        const int*   cbase = cols + blk * EC;
        const float* vbase = vals + blk * EC;
        int i4 = t;
        int4 r4, c4; float4 v4;
        if (i4 < EC4) {
            r4 = *(const int4*)&rbase[i4 * 4];
            c4 = *(const int4*)&cbase[i4 * 4];
            v4 = *(const float4*)&vbase[i4 * 4];
        }
        while (i4 < EC4) {
            int4 rr = r4; int4 cc = c4; float4 vv = v4;
            int ni = i4 + 256;
            if (ni < EC4) {                    // prefetch next iteration
                r4 = *(const int4*)&rbase[ni * 4];
                c4 = *(const int4*)&cbase[ni * 4];
                v4 = *(const float4*)&vbase[ni * 4];
            }
#pragma unroll
            for (int j = 0; j < 4; j++) {
                int r = (&rr.x)[j];
                int b = r >> 6;
                if (b >= b0 && b < b1) {
                    int p = atomicAdd(&cur[b - b0], 1);    // LDS atomic
                    ebuf[p] = make_uint2(((unsigned)(r & 63) << 20) | (unsigned)(&cc.x)[j],
                                         (unsigned)__float_as_int((&vv.x)[j]));
                }
            }
            i4 = ni;
        }
    } else {
        gemm_body<DIN, HID, false, false, true>(X, Wp0, bn0, ab0, bg0,
            nullptr, nullptr, nullptr, nullptr, Hn0b, Hgb, n, blockIdx.x - NCHK * PF, sm);
    }
}

template <int K, int HOUT, bool AFF, bool XBF, bool HNBF>
__global__ __launch_bounds__(256) void gemm_k(
    const void* __restrict__ X, const unsigned short* __restrict__ Wp,
    const float* __restrict__ bnA, const float* __restrict__ bnB, const float* __restrict__ bgA,
    const float* __restrict__ sums, const float* __restrict__ gamma, const float* __restrict__ beta,
    float* __restrict__ Hnf, unsigned short* __restrict__ Hnb, unsigned short* __restrict__ Hgb, int n)
{
    __shared__ alignas(16) char sm[SMSZ];
    gemm_body<K, HOUT, AFF, XBF, HNBF>(X, Wp, bnA, bnB, bgA, sums, gamma, beta,
                                       Hnf, Hnb, Hgb, n, blockIdx.x, sm);
}

// ---------------------------------------------------------------------------
// SpMM phase (block-local CSR staging, shared scratch passed in).
// ---------------------------------------------------------------------------

template <int HH, bool STATS, bool SBF, bool MARKED>
__device__ void spmm_phase(
    const int* __restrict__ rowptr, const int2* __restrict__ cs,
    const unsigned short* __restrict__ Hgb, void* __restrict__ Sv,
    float* __restrict__ stats, const int* __restrict__ mark, int n, int blk, char* sm)
{
    constexpr int L   = HH / 4;     // lanes per group (16 or 8)
    constexpr int GP  = 256 / L;    // groups per block (16 or 32)
    constexpr int RPB = 64;         // rows per block (consecutive)
    constexpr int RPG = RPB / GP;   // rows per group (4 or 2)
    constexpr int ECAP = 1024;      // staged-edge capacity (8KB)
    static_assert(8464 + 2 * GP * HH * 4 <= SMSZ, "smem budget");
    int2*  es  = (int2*)sm;                      // 8192 B
    int*   rp  = (int*)(sm + 8192);              // 260 B (pad to 8464)
    float* rsb = (float*)(sm + 8464);            // GP*HH floats
    float* rqb = rsb + GP * HH;                  // GP*HH floats

    const int t = threadIdx.x;
    const int R0 = blk * RPB;
    if (t <= RPB) rp[t] = rowptr[min(R0 + t, n)];
    __syncthreads();
    const int e0b  = rp[0];
    const int scnt = min(rp[RPB] - e0b, ECAP);
    for (int i = t; i < scnt; i += 256) es[i] = cs[e0b + i];   // coalesced 8B
    __syncthreads();

    const int lane = t % L;
    const int g    = t / L;
    const int c0   = lane * 4;

    float4 sum = make_float4(0.f, 0.f, 0.f, 0.f);
    float4 sq  = make_float4(0.f, 0.f, 0.f, 0.f);

#define SPMM_ROW(FETCH)                                                            \
    {                                                                              \
        int e = le0;                                                               \
        for (; e + 3 < le1; e += 4) {                                              \
            int2 p0 = FETCH(e), p1 = FETCH(e + 1), p2 = FETCH(e + 2), p3 = FETCH(e + 3); \
            float v0 = __int_as_float(p0.y), v1 = __int_as_float(p1.y);            \
            float v2 = __int_as_float(p2.y), v3 = __int_as_float(p3.y);            \
            uint2 h0 = *(const uint2*)&Hgb[(size_t)p0.x * HH + c0];                \
            uint2 h1 = *(const uint2*)&Hgb[(size_t)p1.x * HH + c0];                \
            uint2 h2 = *(const uint2*)&Hgb[(size_t)p2.x * HH + c0];                \
            uint2 h3 = *(const uint2*)&Hgb[(size_t)p3.x * HH + c0];                \
            a0.x += v0 * bf2f_lo(h0.x); a0.y += v0 * bf2f_hi(h0.x);                \
            a0.z += v0 * bf2f_lo(h0.y); a0.w += v0 * bf2f_hi(h0.y);                \
            a1.x += v1 * bf2f_lo(h1.x); a1.y += v1 * bf2f_hi(h1.x);                \
            a1.z += v1 * bf2f_lo(h1.y); a1.w += v1 * bf2f_hi(h1.y);                \
            a2.x += v2 * bf2f_lo(h2.x); a2.y += v2 * bf2f_hi(h2.x);                \
            a2.z += v2 * bf2f_lo(h2.y); a2.w += v2 * bf2f_hi(h2.y);                \
            a3.x += v3 * bf2f_lo(h3.x); a3.y += v3 * bf2f_hi(h3.x);                \
            a3.z += v3 * bf2f_lo(h3.y); a3.w += v3 * bf2f_hi(h3.y);                \
        }                                                                          \
        for (; e < le1; e++) {                                                     \
            int2 p = FETCH(e);                                                     \
            float v = __int_as_float(p.y);                                         \
            uint2 h = *(const uint2*)&Hgb[(size_t)p.x * HH + c0];                  \
            a0.x += v * bf2f_lo(h.x); a0.y += v * bf2f_hi(h.x);                    \
            a0.z += v * bf2f_lo(h.y); a0.w += v * bf2f_hi(h.y);                    \
        }                                                                          \
    }
#define F_LDS(i) es[(i)]
#define F_GLB(i) cs[e0b + (i)]

#pragma unroll
    for (int rr = 0; rr < RPG; rr++) {
        int row = R0 + g * RPG + rr;
        if (row >= n) break;
        if (MARKED && !mark[row]) continue;
        int le0 = rp[g * RPG + rr] - e0b;
        int le1 = rp[g * RPG + rr + 1] - e0b;
        float4 a0, a1, a2, a3;
        if (SBF) {
            uint2 h = *(const uint2*)((const unsigned short*)Sv + (size_t)row * HH + c0);
            a0 = make_float4(bf2f_lo(h.x), bf2f_hi(h.x), bf2f_lo(h.y), bf2f_hi(h.y));
        } else {
            a0 = *(const float4*)((const float*)Sv + (size_t)row * HH + c0);
        }
        a1 = a2 = a3 = make_float4(0.f, 0.f, 0.f, 0.f);
        if (le1 <= scnt) SPMM_ROW(F_LDS) else SPMM_ROW(F_GLB);
        float4 acc = make_float4(a0.x + a1.x + a2.x + a3.x, a0.y + a1.y + a2.y + a3.y,
                                 a0.z + a1.z + a2.z + a3.z, a0.w + a1.w + a2.w + a3.w);
        if (SBF) {
            uint2 o;
            o.x = (unsigned)f2bf(acc.x) | ((unsigned)f2bf(acc.y) << 16);
            o.y = (unsigned)f2bf(acc.z) | ((unsigned)f2bf(acc.w) << 16);
            *(uint2*)((unsigned short*)Sv + (size_t)row * HH + c0) = o;
        } else {
            *(float4*)((float*)Sv + (size_t)row * HH + c0) = acc;
        }
        if (STATS) {
            sum.x += acc.x; sum.y += acc.y; sum.z += acc.z; sum.w += acc.w;
            sq.x += acc.x * acc.x; sq.y += acc.y * acc.y;
            sq.z += acc.z * acc.z; sq.w += acc.w * acc.w;
        }
    }
#undef SPMM_ROW
#undef F_LDS
#undef F_GLB

    if constexpr (STATS) {
        *(float4*)&rsb[g * HH + c0] = sum;
        *(float4*)&rqb[g * HH + c0] = sq;
        __syncthreads();
        if (t < HH) {
            float a = 0.f, b = 0.f;
            for (int w = 0; w < GP; w++) { a += rsb[w * HH + t]; b += rqb[w * HH + t]; }
            int stripe = blk & 7;
            atomicAdd(&stats[stripe * 128 + t], a);
            atomicAdd(&stats[stripe * 128 + HH + t], b);
        }
    }
}

template <int HH, bool STATS, bool SBF, bool MARKED>
__global__ __launch_bounds__(256) void spmm_k(
    const int* __restrict__ rowptr, const int2* __restrict__ cs,
    const unsigned short* __restrict__ Hgb, void* __restrict__ Sv,
    float* __restrict__ stats, const int* __restrict__ mark, int n)
{
    __shared__ alignas(16) char sm[SMSZ];
    spmm_phase<HH, STATS, SBF, MARKED>(rowptr, cs, Hgb, Sv, stats, mark, n, blockIdx.x, sm);
}

__global__ void gather_k(const float* __restrict__ S, const int* __restrict__ idx,
                         float* __restrict__ out, int total4) {
    int j = blockIdx.x * 256 + threadIdx.x;
    if (j < total4) {
        int r = j / (EMB / 4), c4 = (j % (EMB / 4)) * 4;
        *(float4*)&out[(size_t)j * 4] = *(const float4*)&S[(size_t)idx[r] * EMB + c4];
    }
}

// ---------------------------------------------------------------------------
// Cooperative TAIL: gemm1 -> spmm1 -> gemmL -> spmmL -> gather in ONE
// dispatch with grid-wide syncs. Grid = GBM (1563) blocks x 256 thr,
// 17.9KB LDS, <=72 VGPR (launch_bounds 7 waves/EU) -> 7 blocks/CU co-resident.
// ---------------------------------------------------------------------------

__global__ __launch_bounds__(256, 7) void tail_k(
    const unsigned short* nA, const unsigned short* Wp1, const float* ab1,
    const float* sums0, const float* g0, const float* b0,
    unsigned short* nB, unsigned short* Hgb,
    const int* rowptr, const int2* cs, float* sums1,
    const unsigned short* WpL, const float* abL, const float* g1, const float* b1,
    float* HnLf, const int* mark, const int* idx, float* out, int n)
{
    __shared__ alignas(16) char sm[SMSZ];
    const int blk = blockIdx.x;
    cg::grid_group grid = cg::this_grid();

    // Layer 1: BN(S0) folded; [Hn1|Hg1] = relu(bn(S0)) @ [Wn1|Wg1]
    gemm_body<HID, HID, true, true, true>(nA, Wp1, ab1, nullptr, nullptr,
        sums0, g0, b0, nullptr, nB, Hgb, n, blk, sm);
    grid.sync();
    // S1 = Hn1 + ab1 + A@Hg1 (+ stats)
    spmm_phase<HID, true, true, false>(rowptr, cs, Hgb, nB, sums1, nullptr, n, blk, sm);
    grid.sync();
    // Last layer: HnL fp32 = bn(S1)-relu @ WnL; HgL bf16
    gemm_body<HID, EMB, true, true, false>(nB, WpL, abL, nullptr, nullptr,
        sums1, g1, b1, HnLf, nullptr, Hgb, n, blk, sm);
    grid.sync();
    // SL = HnL + A@HgL (marked rows only)
    spmm_phase<EMB, false, false, true>(rowptr, cs, Hgb, HnLf, nullptr, mark, n, blk, sm);
    grid.sync();
    // gather: out[j] = SL[idx[j]]
    int j = blk * 256 + threadIdx.x;
    constexpr int total4 = NIDX * EMB / 4;
    if (j < total4) {
        int r = j / (EMB / 4), c4 = (j % (EMB / 4)) * 4;
        *(float4*)&out[(size_t)j * 4] = *(const float4*)&HnLf[(size_t)idx[r] * EMB + c4];
    }
}

// ---------------------------------------------------------------------------

extern "C" void kernel_launch(void* const* d_in, const int* in_sizes, int n_in,
                              void* d_out, int out_size, void* d_ws, size_t ws_size,
                              hipStream_t stream) {
    const float* features = (const float*)d_in[0];
    const int*   rows     = (const int*)d_in[1];
    const int*   cols     = (const int*)d_in[2];
    const float* vals     = (const float*)d_in[3];
    const int*   idx      = (const int*)d_in[4];
    const float* Wn0 = (const float*)d_in[5];
    const float* bn0 = (const float*)d_in[6];
    const float* Wg0 = (const float*)d_in[7];
    const float* bg0 = (const float*)d_in[8];
    const float* ab0 = (const float*)d_in[9];
    const float* g0  = (const float*)d_in[10];
    const float* b0  = (const float*)d_in[11];
    const float* Wn1 = (const float*)d_in[12];
    const float* Wg1 = (const float*)d_in[13];
    const float* ab1 = (const float*)d_in[14];
    const float* g1  = (const float*)d_in[15];
    const float* b1  = (const float*)d_in[16];
    const float* WnL = (const float*)d_in[17];
    const float* WgL = (const float*)d_in[18];
    const float* abL = (const float*)d_in[19];
    float* out = (float*)d_out;

    // Workspace layout (~65 MB), 16B-aligned sub-buffers.
    float*          HnLf = (float*)d_ws;                        // N x EMB fp32 (HnL/SL)
    unsigned short* nA   = (unsigned short*)(HnLf + (size_t)NNODES * EMB); // Hn0/S0 bf16
    unsigned short* nB   = nA + (size_t)NNODES * HID;           // Hn1/S1 bf16
    unsigned short* Hgb  = nB + (size_t)NNODES * HID;           // Hg (all layers) bf16
    uint2* ebuf  = (uint2*)(Hgb + (size_t)NNODES * HID);        // E x 8B (packed)
    int2*  cs    = (int2*)(ebuf + NEDGES);                      // E (row-sorted payload)
    int*   rowptr = (int*)(cs + NEDGES);                        // N+4
    int*   Bcnt4 = rowptr + (NNODES + 4);                       // NCHK x NB
    int*   BcntT = Bcnt4 + NCHK * NB;                           // NCHK x NB
    int*   bBase = BcntT + NCHK * NB;                           // NB+1 (pad 1568)
    unsigned short* Wp0 = (unsigned short*)(bBase + 1568);      // 16384
    unsigned short* Wp1 = Wp0 + 16384;                          // 8192
    unsigned short* WpL = Wp1 + 8192;                           // 4096
    // ---- single zeroed region: stats | mark | bTot ----
    float* stats = (float*)(WpL + 4096);                        // 2304
    int*   mark  = (int*)(stats + 2304);                        // N
    int*   bTot  = mark + NNODES;                               // 1568
    float* sums0 = stats;
    float* sums1 = stats + 1024;
    size_t zbytes = 2304 * 4 + (size_t)NNODES * 4 + 1568 * 4;

    hipMemsetAsync(stats, 0, zbytes, stream);

    const int GBm = GBM;                    // 1563
    const int MB  = (NIDX + 255) / 256;     // 196

    // K1: per-chunk bucket histogram (+bTot atomics) + mark + W pre-pack.
    histpack_k<<<NCHK + MB + 112, 256, 0, stream>>>(
        rows, Bcnt4, bTot, idx, mark, Wn0, Wg0, Wn1, Wg1, WnL, WgL, Wp0, Wp1, WpL, MB);
    // ONE dispatch: chunk-prefix (blocks 0-6) + bucket-base scan (block 7).
    scan_k<<<8, 256, 0, stream>>>(Bcnt4, BcntT, bTot, bBase);
    part_gemm0_k<<<NCHK * PF + GBm, 256, 0, stream>>>(rows, cols, vals, BcntT, bBase, ebuf,
                                                      features, Wp0, bn0, ab0, bg0,
                                                      nA, Hgb, NNODES);
    // FUSED v2: single-pass bucket sort (LDS) -> rowptr/cs AND S0 = Hn0 + A@Hg0
    bfinal_spmm0_k<<<NB, 256, 0, stream>>>(ebuf, bBase, rowptr, cs, Hgb, nA, sums0, NNODES);

    // ---- Cooperative tail (gemm1 -> spmm1 -> gemmL -> spmmL -> gather) ----
    static int coop_ok = -1;
    if (coop_ok < 0) {
        int dev = 0, sup = 0, ncu = 0, mb = 0;
        hipGetDevice(&dev);
        hipDeviceGetAttribute(&sup, hipDeviceAttributeCooperativeLaunch, dev);
        hipDeviceGetAttribute(&ncu, hipDeviceAttributeMultiprocessorCount, dev);
        hipOccupancyMaxActiveBlocksPerMultiprocessor(&mb, tail_k, 256, 0);
        coop_ok = (sup && (long)mb * ncu >= GBM) ? 1 : 0;
    }
    if (coop_ok == 1) {
        int nn = NNODES;
        void* ka[] = { (void*)&nA, (void*)&Wp1, (void*)&ab1, (void*)&sums0,
                       (void*)&g0, (void*)&b0, (void*)&nB, (void*)&Hgb,
                       (void*)&rowptr, (void*)&cs, (void*)&sums1, (void*)&WpL,
                       (void*)&abL, (void*)&g1, (void*)&b1, (void*)&HnLf,
                       (void*)&mark, (void*)&idx, (void*)&out, (void*)&nn };
        hipError_t e = hipLaunchCooperativeKernel((const void*)tail_k, dim3(GBm), dim3(256),
                                                  ka, 0, stream);
        if (e != hipSuccess) coop_ok = 0;   // fall through to separate launches
    }
    if (coop_ok != 1) {
        gemm_k<HID, HID, true, true, true><<<GBm, 256, 0, stream>>>(
            nA, Wp1, ab1, nullptr, nullptr, sums0, g0, b0, nullptr, nB, Hgb, NNODES);
        spmm_k<HID, true, true, false><<<GBm, 256, 0, stream>>>(rowptr, cs, Hgb, nB, sums1, nullptr, NNODES);
        gemm_k<HID, EMB, true, true, false><<<GBm, 256, 0, stream>>>(
            nB, WpL, abL, nullptr, nullptr, sums1, g1, b1, HnLf, nullptr, Hgb, NNODES);
        spmm_k<EMB, false, false, true><<<GBm, 256, 0, stream>>>(rowptr, cs, Hgb, HnLf, nullptr, mark, NNODES);
        gather_k<<<(NIDX * EMB / 4 + 255) / 256, 256, 0, stream>>>(HnLf, idx, out, NIDX * EMB / 4);
    }
}

// Round 13
// 252.390 us; speedup vs baseline: 1.0857x; 1.0857x over previous
//
#include <hip/hip_runtime.h>

// Problem constants (fixed by the reference).
#define NNODES 100000
#define NEDGES 800000
#define DIN    128
#define HID    64
#define EMB    32
#define NIDX   50000
#define BN_EPS 1e-5f

#define NCHK 64                   // partition chunks (64 -> ~8-edge runs per bucket, 64B)
#define EC   (NEDGES / NCHK)      // 12500 edges per chunk
#define NB   ((NNODES + 63) / 64) // 1563 row-buckets of 64 rows
#define PF   16                   // bucket fractions per chunk (scatter parallelism)
#define NBF  ((NB + PF - 1) / PF) // 98 buckets per fraction

typedef __attribute__((ext_vector_type(8))) short short8;   // 8 bf16 = 4 VGPR
typedef __attribute__((ext_vector_type(4))) float f32x4;    // MFMA C/D

__device__ inline unsigned short f2bf(float f) {            // RNE, matches HW
    unsigned u = __float_as_uint(f);
    unsigned r = u + 0x7FFFu + ((u >> 16) & 1u);
    return (unsigned short)(r >> 16);
}
__device__ inline float bf2f_lo(unsigned u) { return __uint_as_float(u << 16); }
__device__ inline float bf2f_hi(unsigned u) { return __uint_as_float(u & 0xffff0000u); }

// ---------------------------------------------------------------------------
// W pre-pack: fp32 [Wn|Wg] -> bf16 B-fragment-major (GEMM B-loads coalesced).
// ---------------------------------------------------------------------------

__device__ inline void pack_seg(const float* __restrict__ Wn, const float* __restrict__ Wg,
                                unsigned short* __restrict__ Wp, int HOUT, int l2nt, int f) {
    int j = f & 7, lane = (f >> 3) & 63, g = f >> 9;
    int tt = g & ((1 << l2nt) - 1), kb = g >> l2nt;
    int k = kb * 32 + ((lane >> 4) * 8) + j;
    int nn = tt * 16 + (lane & 15);
    float v = (nn < HOUT) ? Wn[k * HOUT + nn] : Wg[k * HOUT + (nn - HOUT)];
    Wp[f] = f2bf(v);
}

// ---------------------------------------------------------------------------
// K1: blocks [0,NCHK): per-chunk bucket histogram -> Bcnt4[chunk][b]
//     + bucket totals bTot[b] via global atomics (breaks prefix/scan dep).
//     blocks [NCHK,NCHK+MB): mark[idx[j]] = 1
//     blocks [NCHK+MB,..): W pre-pack (all 3 layers)  -- all independent.
// ---------------------------------------------------------------------------

__global__ __launch_bounds__(256) void histpack_k(
    const int* __restrict__ rows, int* __restrict__ Bcnt4, int* __restrict__ bTot,
    const int* __restrict__ idx, int* __restrict__ mark,
    const float* Wn0, const float* Wg0, const float* Wn1,
    const float* Wg1, const float* WnL, const float* WgL,
    unsigned short* Wp0, unsigned short* Wp1, unsigned short* WpL, int MB)
{
    int blk = blockIdx.x;
    int t = threadIdx.x;
    if (blk >= NCHK + MB) {
        int f = (blk - NCHK - MB) * 256 + t;
        if (f < 16384)      pack_seg(Wn0, Wg0, Wp0, 64, 3, f);           // 128x128
        else if (f < 24576) pack_seg(Wn1, Wg1, Wp1, 64, 3, f - 16384);   // 64x128
        else if (f < 28672) pack_seg(WnL, WgL, WpL, 32, 2, f - 24576);   // 64x64
        return;
    }
    if (blk >= NCHK) {
        int j = (blk - NCHK) * 256 + t;
        if (j < NIDX) mark[idx[j]] = 1;
        return;
    }
    __shared__ int hist[NB];
    for (int b = t; b < NB; b += 256) hist[b] = 0;
    __syncthreads();
    const int* rbase = rows + blk * EC;
    for (int i4 = t; i4 < EC / 4; i4 += 256) {           // 3125 int4 reads
        int4 r4 = *(const int4*)&rbase[i4 * 4];
        atomicAdd(&hist[r4.x >> 6], 1);
        atomicAdd(&hist[r4.y >> 6], 1);
        atomicAdd(&hist[r4.z >> 6], 1);
        atomicAdd(&hist[r4.w >> 6], 1);
    }
    __syncthreads();
    for (int b = t; b < NB; b += 256) {
        int h = hist[b];
        Bcnt4[blk * NB + b] = h;
        if (h) atomicAdd(&bTot[b], h);                   // device-scope
    }
}

// scan_k: ONE dispatch, two independent jobs (both depend only on histpack):
//   blocks 0..6: per-bucket prefix over chunks -> BcntT[chunk][b]
//   block 7:     exclusive scan of bTot -> bBase (bucket bases)
__global__ __launch_bounds__(256) void scan_k(
    const int* __restrict__ Bcnt4, int* __restrict__ BcntT,
    const int* __restrict__ bTot, int* __restrict__ bBase)
{
    int t = threadIdx.x;
    if (blockIdx.x < 7) {
        int b = blockIdx.x * 256 + t;
        if (b >= NB) return;
        int run = 0;
        for (int c = 0; c < NCHK; c++) {
            BcntT[c * NB + b] = run;     // coalesced read & write
            run += Bcnt4[c * NB + b];
        }
        return;
    }
    __shared__ int s[256];
    int v[7], loc = 0;
#pragma unroll
    for (int i = 0; i < 7; i++) {
        int ix = t * 7 + i;
        v[i] = loc;
        loc += (ix < NB) ? bTot[ix] : 0;
    }
    s[t] = loc;
    __syncthreads();
    for (int off = 1; off < 256; off <<= 1) {
        int a = (t >= off) ? s[t - off] : 0;
        __syncthreads();
        s[t] += a;
        __syncthreads();
    }
    int base = s[t] - loc;
#pragma unroll
    for (int i = 0; i < 7; i++) {
        int ix = t * 7 + i;
        if (ix < NB) bBase[ix] = base + v[i];
    }
    if (t == 255) bBase[NB] = NEDGES;
}

// ---------------------------------------------------------------------------
// bfinal+spmm0 FUSED v2: one block per bucket (64 rows, ~512 edges).
// Single ebuf pass: each thread holds its <=4 edges in named registers while
// building the LDS histogram; after the local scan, scatters them into LDS
// es2[] (bucket-local sorted order); es2 is dumped to cs with fully coalesced
// stores; the spmm0 phase consumes edges straight from LDS (cs never re-read).
// Overflow (>1024 edges/bucket, +22 sigma) falls back to global cs.
// ---------------------------------------------------------------------------

__global__ __launch_bounds__(256) void bfinal_spmm0_k(
    const uint2* __restrict__ ebuf, const int* __restrict__ bBase,
    int* __restrict__ rowptr, int2* __restrict__ cs,
    const unsigned short* __restrict__ Hgb, unsigned short* __restrict__ S,
    float* __restrict__ stats, int n)
{
    constexpr int ECAP = 1024;
    __shared__ int hist[64], sc[64], cur[64];
    __shared__ int2 es2[ECAP];               // bucket-local sorted edges
    __shared__ float rs[16][HID], rq[16][HID];
    int b = blockIdx.x, t = threadIdx.x;
    int e0 = bBase[b], e1 = bBase[b + 1];
    int cnt = e1 - e0;
    int r0 = b << 6;
    if (t < 64) hist[t] = 0;
    __syncthreads();

    // pass 1: load edges once (named registers), build histogram
    uint2 ev0, ev1, ev2, ev3;
    bool h0 = t < cnt, h1 = t + 256 < cnt, h2 = t + 512 < cnt, h3 = t + 768 < cnt;
    if (h0) { ev0 = ebuf[e0 + t];       atomicAdd(&hist[(ev0.x >> 20) & 63], 1); }
    if (h1) { ev1 = ebuf[e0 + t + 256]; atomicAdd(&hist[(ev1.x >> 20) & 63], 1); }
    if (h2) { ev2 = ebuf[e0 + t + 512]; atomicAdd(&hist[(ev2.x >> 20) & 63], 1); }
    if (h3) { ev3 = ebuf[e0 + t + 768]; atomicAdd(&hist[(ev3.x >> 20) & 63], 1); }
    for (int i = t + ECAP; i < cnt; i += 256) {          // overflow tail (rare)
        uint2 v = ebuf[e0 + i];
        atomicAdd(&hist[(v.x >> 20) & 63], 1);
    }
    __syncthreads();
    if (t == 0) {
        int run = 0;                                     // LOCAL (0-based) scan
        for (int j = 0; j < 64; j++) { sc[j] = run; run += hist[j]; }
    }
    __syncthreads();
    if (t < 64) {
        cur[t] = sc[t];
        int r = r0 + t;
        if (r < NNODES) rowptr[r] = e0 + sc[t];
    }
    if (b == NB - 1 && t == 0) rowptr[NNODES] = NEDGES;
    __syncthreads();

    // pass 2: scatter registers -> es2 (LDS), overflow -> cs directly
#define SCAT(V)                                                          \
    {                                                                    \
        int p = atomicAdd(&cur[((V).x >> 20) & 63], 1);                  \
        int2 pay = make_int2((int)((V).x & 0xFFFFF), (int)(V).y);        \
        if (p < ECAP) es2[p] = pay; else cs[e0 + p] = pay;               \
    }
    if (h0) SCAT(ev0)
    if (h1) SCAT(ev1)
    if (h2) SCAT(ev2)
    if (h3) SCAT(ev3)
    for (int i = t + ECAP; i < cnt; i += 256) {
        uint2 v = ebuf[e0 + i];
        SCAT(v)
    }
#undef SCAT
    __syncthreads();                 // es2 complete; overflow cs writes drained

    // pass 3: coalesced dump es2 -> cs (overlaps with spmm0 phase loads)
    int scnt = min(cnt, ECAP);
    for (int i = t; i < scnt; i += 256) cs[e0 + i] = es2[i];

    // ---- spmm0 phase: 16 groups x 16 lanes, 4 consecutive rows per group ----
    const int lane = t & 15, g = t >> 4;
    const int c0 = lane * 4;
    float4 sum = make_float4(0.f, 0.f, 0.f, 0.f);
    float4 sq  = make_float4(0.f, 0.f, 0.f, 0.f);
#define FE(i) ((i) < ECAP ? es2[(i)] : cs[e0 + (i)])
#pragma unroll
    for (int rr = 0; rr < 4; rr++) {
        int lr = g * 4 + rr;
        int row = r0 + lr;
        if (row >= n) break;
        int le0 = sc[lr], le1 = sc[lr] + hist[lr];       // local indices
        uint2 h = *(const uint2*)&S[(size_t)row * HID + c0];
        float4 a0 = make_float4(bf2f_lo(h.x), bf2f_hi(h.x), bf2f_lo(h.y), bf2f_hi(h.y));
        float4 a1 = make_float4(0.f, 0.f, 0.f, 0.f), a2 = a1, a3 = a1;
        int e = le0;
        for (; e + 3 < le1; e += 4) {
            int2 p0 = FE(e), p1 = FE(e + 1), p2 = FE(e + 2), p3 = FE(e + 3);
            float v0 = __int_as_float(p0.y), v1 = __int_as_float(p1.y);
            float v2 = __int_as_float(p2.y), v3 = __int_as_float(p3.y);
            uint2 h0v = *(const uint2*)&Hgb[(size_t)p0.x * HID + c0];
            uint2 h1v = *(const uint2*)&Hgb[(size_t)p1.x * HID + c0];
            uint2 h2v = *(const uint2*)&Hgb[(size_t)p2.x * HID + c0];
            uint2 h3v = *(const uint2*)&Hgb[(size_t)p3.x * HID + c0];
            a0.x += v0 * bf2f_lo(h0v.x); a0.y += v0 * bf2f_hi(h0v.x);
            a0.z += v0 * bf2f_lo(h0v.y); a0.w += v0 * bf2f_hi(h0v.y);
            a1.x += v1 * bf2f_lo(h1v.x); a1.y += v1 * bf2f_hi(h1v.x);
            a1.z += v1 * bf2f_lo(h1v.y); a1.w += v1 * bf2f_hi(h1v.y);
            a2.x += v2 * bf2f_lo(h2v.x); a2.y += v2 * bf2f_hi(h2v.x);
            a2.z += v2 * bf2f_lo(h2v.y); a2.w += v2 * bf2f_hi(h2v.y);
            a3.x += v3 * bf2f_lo(h3v.x); a3.y += v3 * bf2f_hi(h3v.x);
            a3.z += v3 * bf2f_lo(h3v.y); a3.w += v3 * bf2f_hi(h3v.y);
        }
        for (; e < le1; e++) {
            int2 p = FE(e);
            float v = __int_as_float(p.y);
            uint2 hh = *(const uint2*)&Hgb[(size_t)p.x * HID + c0];
            a0.x += v * bf2f_lo(hh.x); a0.y += v * bf2f_hi(hh.x);
            a0.z += v * bf2f_lo(hh.y); a0.w += v * bf2f_hi(hh.y);
        }
        float4 acc = make_float4(a0.x + a1.x + a2.x + a3.x, a0.y + a1.y + a2.y + a3.y,
                                 a0.z + a1.z + a2.z + a3.z, a0.w + a1.w + a2.w + a3.w);
        uint2 o;
        o.x = (unsigned)f2bf(acc.x) | ((unsigned)f2bf(acc.y) << 16);
        o.y = (unsigned)f2bf(acc.z) | ((unsigned)f2bf(acc.w) << 16);
        *(uint2*)&S[(size_t)row * HID + c0] = o;
        sum.x += acc.x; sum.y += acc.y; sum.z += acc.z; sum.w += acc.w;
        sq.x += acc.x * acc.x; sq.y += acc.y * acc.y;
        sq.z += acc.z * acc.z; sq.w += acc.w * acc.w;
    }
#undef FE

    *(float4*)&rs[g][c0] = sum;
    *(float4*)&rq[g][c0] = sq;
    __syncthreads();
    if (t < HID) {
        float a = 0.f, bb = 0.f;
        for (int w = 0; w < 16; w++) { a += rs[w][t]; bb += rq[w][t]; }
        int stripe = b & 7;
        atomicAdd(&stats[stripe * 128 + t], a);
        atomicAdd(&stats[stripe * 128 + HID + t], bb);
    }
}

// ---------------------------------------------------------------------------
// MFMA dual-GEMM body. [Hn | Hg] = act(X) @ [Wn | Wg] (+ per-col biases);
// Hg always bf16 out; Hn bf16 (HNBF) or fp32. X fp32 or bf16 (XBF).
// AFF: BN scale/shift recomputed in-block from striped sums.
// Epilogue: bf16 outputs staged through LDS (reusing Xs) -> coalesced uint4.
// ---------------------------------------------------------------------------

template <int K, int HOUT, bool AFF, bool XBF, bool HNBF>
__device__ void gemm_body(const void* __restrict__ Xv, const unsigned short* __restrict__ Wp,
                          const float* __restrict__ bnA, const float* __restrict__ bnB,
                          const float* __restrict__ bgA,
                          const float* __restrict__ sums, const float* __restrict__ gamma,
                          const float* __restrict__ beta,
                          float* __restrict__ Hnf, unsigned short* __restrict__ Hnb,
                          unsigned short* __restrict__ Hgb, int n, int blk)
{
    constexpr int NT = 2 * HOUT / 16, NKB = K / 32;
    constexpr int RS = K + 8;                       // staging row stride (shorts)
    constexpr int OC = HNBF ? 2 * HOUT : HOUT;      // cols staged through LDS in epilogue
    constexpr int RSE = OC + 8;                     // epilogue row stride (shorts, 16B mult)
    constexpr int XSZ = (RS > RSE) ? RS : RSE;
    __shared__ unsigned short Xs[64 * XSZ];
    __shared__ float sSc[64], sSh[64];

    const int row0 = blk * 64;
    const int t = threadIdx.x;

    if (AFF) {               // in-block BN finalize: 1KB of reads, once per block
        if (t < 64) {
            float sum = 0.f, sq = 0.f;
#pragma unroll
            for (int s = 0; s < 8; s++) { sum += sums[s * 128 + t]; sq += sums[s * 128 + 64 + t]; }
            float m = sum / (float)NNODES;
            float var = sq / (float)NNODES - m * m;
            float sc = gamma[t] * rsqrtf(var + BN_EPS);
            sSc[t] = sc; sSh[t] = beta[t] - m * sc;
        }
        __syncthreads();
    }

    // Stage 64 x K -> bf16 LDS. Loads batched first (row-clamped, unconditional),
    // then convert (+affine+relu) and ds_write.
    constexpr int SIT = K / 32;      // staging iterations per thread (256 thr)
    if constexpr (XBF) {
        uint4 u[SIT];
#pragma unroll
        for (int it = 0; it < SIT; it++) {
            int li = it * 256 + t;
            int rr = row0 + li / (K / 8);
            int k8 = (li % (K / 8)) * 8;
            int rc = rr < n ? rr : n - 1;
            u[it] = *(const uint4*)((const unsigned short*)Xv + (size_t)rc * K + k8);
        }
#pragma unroll
        for (int it = 0; it < SIT; it++) {
            int li = it * 256 + t;
            int r  = li / (K / 8);
            int k8 = (li % (K / 8)) * 8;
            float v[8];
            v[0] = bf2f_lo(u[it].x); v[1] = bf2f_hi(u[it].x);
            v[2] = bf2f_lo(u[it].y); v[3] = bf2f_hi(u[it].y);
            v[4] = bf2f_lo(u[it].z); v[5] = bf2f_hi(u[it].z);
            v[6] = bf2f_lo(u[it].w); v[7] = bf2f_hi(u[it].w);
            if (AFF) {
#pragma unroll
                for (int i = 0; i < 8; i++) v[i] = fmaxf(v[i] * sSc[k8 + i] + sSh[k8 + i], 0.f);
            }
            uint4 o;
            o.x = (unsigned)f2bf(v[0]) | ((unsigned)f2bf(v[1]) << 16);
            o.y = (unsigned)f2bf(v[2]) | ((unsigned)f2bf(v[3]) << 16);
            o.z = (unsigned)f2bf(v[4]) | ((unsigned)f2bf(v[5]) << 16);
            o.w = (unsigned)f2bf(v[6]) | ((unsigned)f2bf(v[7]) << 16);
            *(uint4*)&Xs[r * RS + k8] = o;
        }
    } else {
        const float* Xf = (const float*)Xv;
        float4 a[SIT], b[SIT];
#pragma unroll
        for (int it = 0; it < SIT; it++) {
            int li = it * 256 + t;
            int rr = row0 + li / (K / 8);
            int k8 = (li % (K / 8)) * 8;
            int rc = rr < n ? rr : n - 1;
            a[it] = *(const float4*)&Xf[(size_t)rc * K + k8];
            b[it] = *(const float4*)&Xf[(size_t)rc * K + k8 + 4];
        }
#pragma unroll
        for (int it = 0; it < SIT; it++) {
            int li = it * 256 + t;
            int r  = li / (K / 8);
            int k8 = (li % (K / 8)) * 8;
            float v[8] = { a[it].x, a[it].y, a[it].z, a[it].w,
                           b[it].x, b[it].y, b[it].z, b[it].w };
            if (AFF) {
#pragma unroll
                for (int i = 0; i < 8; i++) v[i] = fmaxf(v[i] * sSc[k8 + i] + sSh[k8 + i], 0.f);
            }
            uint4 o;
            o.x = (unsigned)f2bf(v[0]) | ((unsigned)f2bf(v[1]) << 16);
            o.y = (unsigned)f2bf(v[2]) | ((unsigned)f2bf(v[3]) << 16);
            o.z = (unsigned)f2bf(v[4]) | ((unsigned)f2bf(v[5]) << 16);
            o.w = (unsigned)f2bf(v[6]) | ((unsigned)f2bf(v[7]) << 16);
            *(uint4*)&Xs[r * RS + k8] = o;
        }
    }
    __syncthreads();

    const int wave = t >> 6, lane = t & 63;
    const int q = lane >> 4, mrow = lane & 15;

    f32x4 acc[NT];
#pragma unroll
    for (int i = 0; i < NT; i++) acc[i] = (f32x4){0.f, 0.f, 0.f, 0.f};

    const short8* wp8 = (const short8*)Wp;
#pragma unroll
    for (int kb = 0; kb < NKB; kb++) {
        short8 va = *(const short8*)&Xs[(wave * 16 + mrow) * RS + kb * 32 + q * 8];
#pragma unroll
        for (int tt = 0; tt < NT; tt++) {
            short8 vb = wp8[(kb * NT + tt) * 64 + lane];   // coalesced dwordx4
            acc[tt] = __builtin_amdgcn_mfma_f32_16x16x32_bf16(va, vb, acc[tt], 0, 0, 0);
        }
    }

    // Epilogue. C/D: col = lane&15 (tile tt), row = q*4 + reg.
    // bf16 outputs -> LDS (reuse Xs) -> coalesced uint4 stores.
    __syncthreads();          // all waves done reading staging Xs
#pragma unroll
    for (int tt = 0; tt < NT; tt++) {
        int nglob = tt * 16 + mrow;
        bool nside = (nglob < HOUT);
        int c = nside ? nglob : (nglob - HOUT);
        float bias = 0.f;
        if (nside) {
            if (bnA) bias += bnA[c];
            if (bnB) bias += bnB[c];
        } else if (bgA) {
            bias += bgA[c];
        }
        if (HNBF || !nside) {
            int cc = HNBF ? nglob : c;
#pragma unroll
            for (int r = 0; r < 4; r++)
                Xs[(wave * 16 + q * 4 + r) * RSE + cc] = f2bf(acc[tt][r] + bias);
        } else {
            // fp32 Hn half (last layer only): direct stores
#pragma unroll
            for (int r = 0; r < 4; r++) {
                int rr = row0 + wave * 16 + q * 4 + r;
                if (rr < n) Hnf[(size_t)rr * HOUT + c] = acc[tt][r] + bias;
            }
        }
    }
    __syncthreads();
    constexpr int J = OC / 8;                 // uint4 per row
#pragma unroll
    for (int u2 = 0; u2 < (64 * J) / 256; u2++) {
        int li = u2 * 256 + t;
        int r = li / J, j = li % J;
        int rr = row0 + r;
        if (rr < n) {
            uint4 v = *(const uint4*)&Xs[r * RSE + j * 8];
            int c8 = j * 8;
            if (HNBF && c8 < HOUT)
                *(uint4*)&Hnb[(size_t)rr * HOUT + c8] = v;
            else
                *(uint4*)&Hgb[(size_t)rr * HOUT + (HNBF ? c8 - HOUT : c8)] = v;
        }
    }
}

// K_C: blocks [0,NCHK*PF): bucket-partition. Each chunk is handled by PF
//      blocks; sibling blocks are mapped chunk = i % NCHK, pf = i / NCHK so
//      all PF siblings of a chunk share i%8 (same XCD under round-robin
//      dispatch) -> the chunk's rows/cols/vals are fetched once per XCD L2.
//      Scan loop software-pipelined: next iteration's int4 loads issue before
//      processing current hits (hides L2/L3 latency across iterations).
//      blocks [NCHK*PF,..): layer-0 dual GEMM (co-scheduled, independent).
__global__ __launch_bounds__(256) void part_gemm0_k(
    const int* __restrict__ rows, const int* __restrict__ cols,
    const float* __restrict__ vals, const int* __restrict__ BcntT,
    const int* __restrict__ bBase, uint2* __restrict__ ebuf,
    const float* __restrict__ X, const unsigned short* __restrict__ Wp0,
    const float* __restrict__ bn0, const float* __restrict__ ab0, const float* __restrict__ bg0,
    unsigned short* __restrict__ Hn0b, unsigned short* __restrict__ Hgb, int n)
{
    if ((int)blockIdx.x < NCHK * PF) {
        __shared__ int cur[NBF];
        int t = threadIdx.x;
        int blk = blockIdx.x % NCHK;          // sibling co-location: i%8 == blk%8
        int pf  = blockIdx.x / NCHK;
        int b0 = pf * NBF, b1 = (pf == PF - 1) ? NB : (b0 + NBF);
        for (int b = b0 + t; b < b1; b += 256)
            cur[b - b0] = bBase[b] + BcntT[blk * NB + b];
        __syncthreads();
        constexpr int EC4 = EC / 4;           // 3125 int4 reads per chunk stream
        const int*   rbase = rows + blk * EC;
        const int*   cbase = cols + blk * EC;
        const float* vbase = vals + blk * EC;
        int i4 = t;
        int4 r4, c4; float4 v4;
        if (i4 < EC4) {
            r4 = *(const int4*)&rbase[i4 * 4];
            c4 = *(const int4*)&cbase[i4 * 4];
            v4 = *(const float4*)&vbase[i4 * 4];
        }
        while (i4 < EC4) {
            int4 rr = r4; int4 cc = c4; float4 vv = v4;
            int ni = i4 + 256;
            if (ni < EC4) {                    // prefetch next iteration
                r4 = *(const int4*)&rbase[ni * 4];
                c4 = *(const int4*)&cbase[ni * 4];
                v4 = *(const float4*)&vbase[ni * 4];
            }
#pragma unroll
            for (int j = 0; j < 4; j++) {
                int r = (&rr.x)[j];
                int b = r >> 6;
                if (b >= b0 && b < b1) {
                    int p = atomicAdd(&cur[b - b0], 1);    // LDS atomic
                    ebuf[p] = make_uint2(((unsigned)(r & 63) << 20) | (unsigned)(&cc.x)[j],
                                         (unsigned)__float_as_int((&vv.x)[j]));
                }
            }
            i4 = ni;
        }
    } else {
        gemm_body<DIN, HID, false, false, true>(X, Wp0, bn0, ab0, bg0,
            nullptr, nullptr, nullptr, nullptr, Hn0b, Hgb, n, blockIdx.x - NCHK * PF);
    }
}

template <int K, int HOUT, bool AFF, bool XBF, bool HNBF>
__global__ __launch_bounds__(256) void gemm_k(
    const void* __restrict__ X, const unsigned short* __restrict__ Wp,
    const float* __restrict__ bnA, const float* __restrict__ bnB, const float* __restrict__ bgA,
    const float* __restrict__ sums, const float* __restrict__ gamma, const float* __restrict__ beta,
    float* __restrict__ Hnf, unsigned short* __restrict__ Hnb, unsigned short* __restrict__ Hgb, int n)
{
    gemm_body<K, HOUT, AFF, XBF, HNBF>(X, Wp, bnA, bnB, bgA, sums, gamma, beta,
                                       Hnf, Hnb, Hgb, n, blockIdx.x);
}

// ---------------------------------------------------------------------------
// SpMM v2 (block-local CSR staging): each block owns 64 CONSECUTIVE rows;
// stages rowptr[65] + the block's whole edge segment (~512 edges) into LDS
// with coalesced loads; groups then read edges from LDS (broadcast,
// conflict-free) and issue only the Hgb gathers. Overflow (>1024 edges)
// falls back to direct global reads per row.
// ---------------------------------------------------------------------------

template <int HH, bool STATS, bool SBF, bool MARKED>
__global__ __launch_bounds__(256) void spmm_k(
    const int* __restrict__ rowptr, const int2* __restrict__ cs,
    const unsigned short* __restrict__ Hgb, void* __restrict__ Sv,
    float* __restrict__ stats, const int* __restrict__ mark, int n)
{
    constexpr int L   = HH / 4;     // lanes per group (16 or 8)
    constexpr int GP  = 256 / L;    // groups per block (16 or 32)
    constexpr int RPB = 64;         // rows per block (consecutive)
    constexpr int RPG = RPB / GP;   // rows per group (4 or 2)
    constexpr int ECAP = 1024;      // staged-edge capacity (8KB)
    __shared__ int2 es[ECAP];
    __shared__ int  rp[RPB + 1];

    const int t = threadIdx.x;
    const int R0 = blockIdx.x * RPB;
    if (t <= RPB) rp[t] = rowptr[min(R0 + t, n)];
    __syncthreads();
    const int e0b  = rp[0];
    const int scnt = min(rp[RPB] - e0b, ECAP);
    for (int i = t; i < scnt; i += 256) es[i] = cs[e0b + i];   // coalesced 8B
    __syncthreads();

    const int lane = t % L;
    const int g    = t / L;
    const int c0   = lane * 4;

    float4 sum = make_float4(0.f, 0.f, 0.f, 0.f);
    float4 sq  = make_float4(0.f, 0.f, 0.f, 0.f);

#define SPMM_ROW(FETCH)                                                            \
    {                                                                              \
        int e = le0;                                                               \
        for (; e + 3 < le1; e += 4) {                                              \
            int2 p0 = FETCH(e), p1 = FETCH(e + 1), p2 = FETCH(e + 2), p3 = FETCH(e + 3); \
            float v0 = __int_as_float(p0.y), v1 = __int_as_float(p1.y);            \
            float v2 = __int_as_float(p2.y), v3 = __int_as_float(p3.y);            \
            uint2 h0 = *(const uint2*)&Hgb[(size_t)p0.x * HH + c0];                \
            uint2 h1 = *(const uint2*)&Hgb[(size_t)p1.x * HH + c0];                \
            uint2 h2 = *(const uint2*)&Hgb[(size_t)p2.x * HH + c0];                \
            uint2 h3 = *(const uint2*)&Hgb[(size_t)p3.x * HH + c0];                \
            a0.x += v0 * bf2f_lo(h0.x); a0.y += v0 * bf2f_hi(h0.x);                \
            a0.z += v0 * bf2f_lo(h0.y); a0.w += v0 * bf2f_hi(h0.y);                \
            a1.x += v1 * bf2f_lo(h1.x); a1.y += v1 * bf2f_hi(h1.x);                \
            a1.z += v1 * bf2f_lo(h1.y); a1.w += v1 * bf2f_hi(h1.y);                \
            a2.x += v2 * bf2f_lo(h2.x); a2.y += v2 * bf2f_hi(h2.x);                \
            a2.z += v2 * bf2f_lo(h2.y); a2.w += v2 * bf2f_hi(h2.y);                \
            a3.x += v3 * bf2f_lo(h3.x); a3.y += v3 * bf2f_hi(h3.x);                \
            a3.z += v3 * bf2f_lo(h3.y); a3.w += v3 * bf2f_hi(h3.y);                \
        }                                                                          \
        for (; e < le1; e++) {                                                     \
            int2 p = FETCH(e);                                                     \
            float v = __int_as_float(p.y);                                         \
            uint2 h = *(const uint2*)&Hgb[(size_t)p.x * HH + c0];                  \
            a0.x += v * bf2f_lo(h.x); a0.y += v * bf2f_hi(h.x);                    \
            a0.z += v * bf2f_lo(h.y); a0.w += v * bf2f_hi(h.y);                    \
        }                                                                          \
    }
#define F_LDS(i) es[(i)]
#define F_GLB(i) cs[e0b + (i)]

#pragma unroll
    for (int rr = 0; rr < RPG; rr++) {
        int row = R0 + g * RPG + rr;
        if (row >= n) break;
        if (MARKED && !mark[row]) continue;
        int le0 = rp[g * RPG + rr] - e0b;
        int le1 = rp[g * RPG + rr + 1] - e0b;
        float4 a0, a1, a2, a3;
        if (SBF) {
            uint2 h = *(const uint2*)((const unsigned short*)Sv + (size_t)row * HH + c0);
            a0 = make_float4(bf2f_lo(h.x), bf2f_hi(h.x), bf2f_lo(h.y), bf2f_hi(h.y));
        } else {
            a0 = *(const float4*)((const float*)Sv + (size_t)row * HH + c0);
        }
        a1 = a2 = a3 = make_float4(0.f, 0.f, 0.f, 0.f);
        if (le1 <= scnt) SPMM_ROW(F_LDS) else SPMM_ROW(F_GLB);
        float4 acc = make_float4(a0.x + a1.x + a2.x + a3.x, a0.y + a1.y + a2.y + a3.y,
                                 a0.z + a1.z + a2.z + a3.z, a0.w + a1.w + a2.w + a3.w);
        if (SBF) {
            uint2 o;
            o.x = (unsigned)f2bf(acc.x) | ((unsigned)f2bf(acc.y) << 16);
            o.y = (unsigned)f2bf(acc.z) | ((unsigned)f2bf(acc.w) << 16);
            *(uint2*)((unsigned short*)Sv + (size_t)row * HH + c0) = o;
        } else {
            *(float4*)((float*)Sv + (size_t)row * HH + c0) = acc;
        }
        if (STATS) {
            sum.x += acc.x; sum.y += acc.y; sum.z += acc.z; sum.w += acc.w;
            sq.x += acc.x * acc.x; sq.y += acc.y * acc.y;
            sq.z += acc.z * acc.z; sq.w += acc.w * acc.w;
        }
    }
#undef SPMM_ROW
#undef F_LDS
#undef F_GLB

    if constexpr (STATS) {
        __shared__ float rs[GP][HH];
        __shared__ float rq[GP][HH];
        *(float4*)&rs[g][c0] = sum;
        *(float4*)&rq[g][c0] = sq;
        __syncthreads();
        if (threadIdx.x < HH) {
            float a = 0.f, b = 0.f;
            for (int w = 0; w < GP; w++) { a += rs[w][threadIdx.x]; b += rq[w][threadIdx.x]; }
            int stripe = blockIdx.x & 7;
            atomicAdd(&stats[stripe * 128 + threadIdx.x], a);
            atomicAdd(&stats[stripe * 128 + HH + threadIdx.x], b);
        }
    }
}

__global__ void gather_k(const float* __restrict__ S, const int* __restrict__ idx,
                         float* __restrict__ out, int total4) {
    int j = blockIdx.x * 256 + threadIdx.x;
    if (j < total4) {
        int r = j / (EMB / 4), c4 = (j % (EMB / 4)) * 4;
        *(float4*)&out[(size_t)j * 4] = *(const float4*)&S[(size_t)idx[r] * EMB + c4];
    }
}

// ---------------------------------------------------------------------------

extern "C" void kernel_launch(void* const* d_in, const int* in_sizes, int n_in,
                              void* d_out, int out_size, void* d_ws, size_t ws_size,
                              hipStream_t stream) {
    const float* features = (const float*)d_in[0];
    const int*   rows     = (const int*)d_in[1];
    const int*   cols     = (const int*)d_in[2];
    const float* vals     = (const float*)d_in[3];
    const int*   idx      = (const int*)d_in[4];
    const float* Wn0 = (const float*)d_in[5];
    const float* bn0 = (const float*)d_in[6];
    const float* Wg0 = (const float*)d_in[7];
    const float* bg0 = (const float*)d_in[8];
    const float* ab0 = (const float*)d_in[9];
    const float* g0  = (const float*)d_in[10];
    const float* b0  = (const float*)d_in[11];
    const float* Wn1 = (const float*)d_in[12];
    const float* Wg1 = (const float*)d_in[13];
    const float* ab1 = (const float*)d_in[14];
    const float* g1  = (const float*)d_in[15];
    const float* b1  = (const float*)d_in[16];
    const float* WnL = (const float*)d_in[17];
    const float* WgL = (const float*)d_in[18];
    const float* abL = (const float*)d_in[19];
    float* out = (float*)d_out;

    // Workspace layout (~65 MB), 16B-aligned sub-buffers.
    float*          HnLf = (float*)d_ws;                        // N x EMB fp32 (HnL/SL)
    unsigned short* nA   = (unsigned short*)(HnLf + (size_t)NNODES * EMB); // Hn0/S0 bf16
    unsigned short* nB   = nA + (size_t)NNODES * HID;           // Hn1/S1 bf16
    unsigned short* Hgb  = nB + (size_t)NNODES * HID;           // Hg (all layers) bf16
    uint2* ebuf  = (uint2*)(Hgb + (size_t)NNODES * HID);        // E x 8B (packed)
    int2*  cs    = (int2*)(ebuf + NEDGES);                      // E (row-sorted payload)
    int*   rowptr = (int*)(cs + NEDGES);                        // N+4
    int*   Bcnt4 = rowptr + (NNODES + 4);                       // NCHK x NB
    int*   BcntT = Bcnt4 + NCHK * NB;                           // NCHK x NB
    int*   bBase = BcntT + NCHK * NB;                           // NB+1 (pad 1568)
    unsigned short* Wp0 = (unsigned short*)(bBase + 1568);      // 16384
    unsigned short* Wp1 = Wp0 + 16384;                          // 8192
    unsigned short* WpL = Wp1 + 8192;                           // 4096
    // ---- single zeroed region: stats | mark | bTot ----
    float* stats = (float*)(WpL + 4096);                        // 2304
    int*   mark  = (int*)(stats + 2304);                        // N
    int*   bTot  = mark + NNODES;                               // 1568
    float* sums0 = stats;
    float* sums1 = stats + 1024;
    size_t zbytes = 2304 * 4 + (size_t)NNODES * 4 + 1568 * 4;

    hipMemsetAsync(stats, 0, zbytes, stream);

    const int GBm = (NNODES + 63) / 64;     // 1563
    const int MB  = (NIDX + 255) / 256;     // 196

    // K1: per-chunk bucket histogram (+bTot atomics) + mark + W pre-pack.
    histpack_k<<<NCHK + MB + 112, 256, 0, stream>>>(
        rows, Bcnt4, bTot, idx, mark, Wn0, Wg0, Wn1, Wg1, WnL, WgL, Wp0, Wp1, WpL, MB);
    // ONE dispatch: chunk-prefix (blocks 0-6) + bucket-base scan (block 7).
    scan_k<<<8, 256, 0, stream>>>(Bcnt4, BcntT, bTot, bBase);
    part_gemm0_k<<<NCHK * PF + GBm, 256, 0, stream>>>(rows, cols, vals, BcntT, bBase, ebuf,
                                                      features, Wp0, bn0, ab0, bg0,
                                                      nA, Hgb, NNODES);
    // FUSED v2: single-pass bucket sort (LDS) -> rowptr/cs AND S0 = Hn0 + A@Hg0
    bfinal_spmm0_k<<<NB, 256, 0, stream>>>(ebuf, bBase, rowptr, cs, Hgb, nA, sums0, NNODES);

    // Layer 1: BN finalize folded into gemm; S1 = Hn1 + ab1 + A@Hg1
    gemm_k<HID, HID, true, true, true><<<GBm, 256, 0, stream>>>(
        nA, Wp1, ab1, nullptr, nullptr, sums0, g0, b0, nullptr, nB, Hgb, NNODES);
    spmm_k<HID, true, true, false><<<GBm, 256, 0, stream>>>(rowptr, cs, Hgb, nB, sums1, nullptr, NNODES);

    // Last layer: HnL fp32; aggregate only rows referenced by idx.
    gemm_k<HID, EMB, true, true, false><<<GBm, 256, 0, stream>>>(
        nB, WpL, abL, nullptr, nullptr, sums1, g1, b1, HnLf, nullptr, Hgb, NNODES);
    spmm_k<EMB, false, false, true><<<GBm, 256, 0, stream>>>(rowptr, cs, Hgb, HnLf, nullptr, mark, NNODES);

    gather_k<<<(NIDX * EMB / 4 + 255) / 256, 256, 0, stream>>>(HnLf, idx, out, NIDX * EMB / 4);
}